// Round 4
// baseline (163.670 us; speedup 1.0000x reference)
//
#include <hip/hip_runtime.h>
#include <hip/hip_bf16.h>

#define BATCH 16384
#define FIN   768
#define FOUT  512

#define BK 64
#define NT (FIN / BK)   // 12 K-iterations
#define BM 128          // batch rows per block -> 256 GEMM rows (stm+nstm)
#define BN 256          // feature cols per block (N-split x2)

typedef __attribute__((ext_vector_type(8))) short short8;
typedef __attribute__((ext_vector_type(4))) float floatx4;

// packed fp32x2 -> bf16x2, round-to-nearest-even (gfx940+ VOP3)
__device__ __forceinline__ unsigned int cvt_pk_bf16(float a, float b) {
    unsigned int r;
    asm("v_cvt_pk_bf16_f32 %0, %1, %2" : "=v"(r) : "v"(a), "v"(b));
    return r;
}

// async 16B global -> LDS DMA; HW scatters lane i to ldsbase + i*16
__device__ __forceinline__ void load_lds_16(const void* g, void* l) {
    __builtin_amdgcn_global_load_lds(
        (const __attribute__((address_space(1))) unsigned int*)g,
        (__attribute__((address_space(3))) unsigned int*)l,
        16, 0, 0);
}

// one-shot W1 fp32 -> bf16 (393216 elems, 8 per thread, 192 blocks)
__global__ __launch_bounds__(256) void cvt_w1(
    const float* __restrict__ W1, unsigned short* __restrict__ W1b)
{
    int base = (blockIdx.x * 256 + threadIdx.x) * 8;
    float4 a = *(const float4*)(W1 + base);
    float4 b = *(const float4*)(W1 + base + 4);
    uint4 o;
    o.x = cvt_pk_bf16(a.x, a.y); o.y = cvt_pk_bf16(a.z, a.w);
    o.z = cvt_pk_bf16(b.x, b.y); o.w = cvt_pk_bf16(b.z, b.w);
    *(uint4*)(W1b + base) = o;
}

// 256 blocks x 512 threads, 1 block/CU (128 KB LDS). m201-template geometry:
// 8 waves as 2(M) x 4(N), each owning a 128x64 tile (8x4 frags of 16x16x32
// bf16 MFMA, acc 128 regs). vs round-3's 16x 64x64 tiles this cuts LDS frag
// reads 256->192 KB/tile (B re-read 2x not 4x) and gives each wave a 24-read
// + 64-MFMA straight-line stream for compiler pipelining (2 waves/SIMD).
// XCD-pair swizzle: sbid=(bid&7)*32+(bid>>3) puts the two N-split blocks that
// share A-rows on the SAME XCD -> second block's A reads hit L2 (FETCH/2).
// Schedule + swizzles verbatim from the verified round-3 kernel:
//   [publish A(t)] barrier [issue A-load(t+1) + B-DMA(t+1)] [MFMA tile t]
__global__ __launch_bounds__(512, 2) void pn_gemm(
    const float* __restrict__ stm, const float* __restrict__ nstm,
    const unsigned short* __restrict__ W1b, const float* __restrict__ b1,
    const float* __restrict__ W2, float* __restrict__ P)
{
    __shared__ __align__(16) unsigned short As[2][256 * 64];  // 2 x 32 KB
    __shared__ __align__(16) unsigned short Bs[2][256 * 64];  // 2 x 32 KB

    const int tid  = threadIdx.x;
    const int lane = tid & 63;
    const int wave = tid >> 6;    // 0..7
    const int wr   = wave >> 2;   // row band: GEMM rows wr*128 .. +127
    const int wc   = wave & 3;    // col tile: cols wc*64 .. +63 (within BN)
    const int quad = lane >> 4;
    const int l16  = lane & 15;

    // XCD-pair swizzle (bijective: 256 blocks, 8 XCDs): logical ids are
    // contiguous per XCD chunk, so pair (2p,2p+1) shares one XCD's L2.
    const int sbid  = (blockIdx.x & 7) * 32 + (blockIdx.x >> 3);
    const int bm    = sbid >> 1;
    const int n_idx = sbid & 1;
    const int b0    = bm * BM;        // batch rows owned by this block
    const int n0    = n_idx * BN;     // feature cols owned by this block

    // ---- A staging: thread covers row arow, global chunks h*4 .. h*4+3
    const int arow = tid >> 1;        // 0..255
    const int h    = tid & 1;         // which half of the 8 chunks
    const float* aSrc =
        ((arow < BM) ? stm  + (size_t)(b0 + arow) * FIN
                     : nstm + (size_t)(b0 + arow - BM) * FIN) + h * 32;
    int aOff[4];
    #pragma unroll
    for (int c = 0; c < 4; ++c)
        aOff[c] = arow * 64 + (((h * 4 + c) ^ (arow & 7)) * 8);  // swizzled

    // ---- B staging: 4 DMA instrs/thread, J = wave*4+i covers rows J*8..+7.
    // DMA writes lane l -> base + l*16 (row l>>3, slot l&7); source chunk is
    // pre-swizzled so LDS holds slot = chunk ^ (row&7).
    const int brow = lane >> 3;                 // row within 8-group
    const int bch  = (lane & 7) ^ brow;         // swizzled SOURCE chunk
    const unsigned short* bSrc =
        W1b + (size_t)(n0 + brow) * FIN + bch * 8;

    floatx4 acc[8][4];
    #pragma unroll
    for (int i = 0; i < 8; ++i)
        #pragma unroll
        for (int j = 0; j < 4; ++j)
            acc[i][j] = (floatx4)0.0f;

    // ---- prologue: stage tile 0
    float4 ap[8];
    #pragma unroll
    for (int c = 0; c < 4; ++c) {
        ap[2 * c]     = *(const float4*)(aSrc + c * 8);
        ap[2 * c + 1] = *(const float4*)(aSrc + c * 8 + 4);
    }
    #pragma unroll
    for (int i = 0; i < 4; ++i) {
        const int J = wave * 4 + i;
        load_lds_16(bSrc + (size_t)(J * 8) * FIN, &Bs[0][J * 512]);
    }

    for (int t = 0; t < NT; ++t) {
        const int cur = t & 1;
        const int nxt = cur ^ 1;

        // publish A(t) (regs loaded last iter; As[cur] reads drained at barrier t-1)
        #pragma unroll
        for (int c = 0; c < 4; ++c) {
            uint4 o;
            o.x = cvt_pk_bf16(ap[2 * c].x, ap[2 * c].y);
            o.y = cvt_pk_bf16(ap[2 * c].z, ap[2 * c].w);
            o.z = cvt_pk_bf16(ap[2 * c + 1].x, ap[2 * c + 1].y);
            o.w = cvt_pk_bf16(ap[2 * c + 1].z, ap[2 * c + 1].w);
            *(uint4*)(&As[cur][aOff[c]]) = o;
        }
        __syncthreads();   // drains B-DMA(t) + A-store(t); protects tile t-1 buffers

        // issue staging for t+1 — lands during tile t's compute.
        // A-loads FIRST so their register-dep wait doesn't drain the B-DMAs.
        if (t + 1 < NT) {
            const int kn = (t + 1) * BK;
            #pragma unroll
            for (int c = 0; c < 4; ++c) {
                ap[2 * c]     = *(const float4*)(aSrc + kn + c * 8);
                ap[2 * c + 1] = *(const float4*)(aSrc + kn + c * 8 + 4);
            }
            #pragma unroll
            for (int i = 0; i < 4; ++i) {
                const int J = wave * 4 + i;
                load_lds_16(bSrc + (size_t)(J * 8) * FIN + kn, &Bs[nxt][J * 512]);
            }
        }

        // compute tile t: two K=32 halves; per half, 12 ds_read + 32 MFMA
        #pragma unroll
        for (int kk = 0; kk < 2; ++kk) {
            const int c = kk * 4 + quad;   // chunk index 0..7
            short8 af[8], bfr[4];
            #pragma unroll
            for (int mi = 0; mi < 8; ++mi) {
                const int m = wr * 128 + mi * 16 + l16;
                af[mi] = *(const short8*)(&As[cur][m * 64 + ((c ^ (m & 7)) * 8)]);
            }
            #pragma unroll
            for (int ni = 0; ni < 4; ++ni) {
                const int n = wc * 64 + ni * 16 + l16;
                bfr[ni] = *(const short8*)(&Bs[cur][n * 64 + ((c ^ (n & 7)) * 8)]);
            }
            __builtin_amdgcn_s_setprio(1);
            #pragma unroll
            for (int mi = 0; mi < 8; ++mi)
                #pragma unroll
                for (int ni = 0; ni < 4; ++ni)
                    acc[mi][ni] = __builtin_amdgcn_mfma_f32_16x16x32_bf16(
                        af[mi], bfr[ni], acc[mi][ni], 0, 0, 0);
            __builtin_amdgcn_s_setprio(0);
        }
    }

    // ---- fused epilogue. C/D layout: col = lane&15, row = quad*4 + reg.
    // GEMM rows 0-127 (wr=0) = stm -> W2[0..511];
    // rows 128-255 (wr=1) = nstm -> W2[512..1023]. wr is wave-uniform.
    float b1v[4], w2v[4];
    const float* w2base = (wr == 0) ? W2 : W2 + FOUT;
    #pragma unroll
    for (int ni = 0; ni < 4; ++ni) {
        int col = n0 + wc * 64 + ni * 16 + l16;
        b1v[ni] = b1[col];
        w2v[ni] = w2base[col];
    }

    __syncthreads();                 // all MFMA LDS reads done; reuse As
    float* Epi = (float*)As;         // [256 rows][4 wave-cols] partials (4 KB)

    #pragma unroll
    for (int mi = 0; mi < 8; ++mi) {
        #pragma unroll
        for (int r = 0; r < 4; ++r) {
            float s = 0.0f;
            #pragma unroll
            for (int ni = 0; ni < 4; ++ni) {
                float hh = acc[mi][ni][r] + b1v[ni];
                hh = fminf(fmaxf(hh, 0.0f), 1.0f);
                s += hh * w2v[ni];
            }
            s += __shfl_xor(s, 1);
            s += __shfl_xor(s, 2);
            s += __shfl_xor(s, 4);
            s += __shfl_xor(s, 8);
            if (l16 == 0) {
                Epi[(wr * 128 + mi * 16 + quad * 4 + r) * 4 + wc] = s;
            }
        }
    }
    __syncthreads();

    // batch row i partial over this block's 256 features =
    // stm-row i partials (rows 0-127) + nstm-row i partials (128-255)
    if (tid < BM) {
        float x = 0.0f;
        #pragma unroll
        for (int j = 0; j < 4; ++j)
            x += Epi[tid * 4 + j] + Epi[(tid + BM) * 4 + j];
        P[n_idx * BATCH + b0 + tid] = x;
    }
}

// sum the two N-half partials + bias, sigmoid
__global__ __launch_bounds__(256) void finish(
    const float* __restrict__ P, const float* __restrict__ b2,
    float* __restrict__ out)
{
    int i = blockIdx.x * 256 + threadIdx.x;
    float x = b2[0] + P[i] + P[BATCH + i];
    out[i] = 1.0f / (1.0f + expf(-x));
}

extern "C" void kernel_launch(void* const* d_in, const int* in_sizes, int n_in,
                              void* d_out, int out_size, void* d_ws, size_t ws_size,
                              hipStream_t stream)
{
    (void)in_sizes; (void)n_in; (void)out_size; (void)ws_size;
    const float* stm  = (const float*)d_in[0];
    const float* nstm = (const float*)d_in[1];
    const float* W1   = (const float*)d_in[2];
    const float* b1   = (const float*)d_in[3];
    const float* W2   = (const float*)d_in[4];
    const float* b2   = (const float*)d_in[5];
    float* out = (float*)d_out;
    unsigned short* W1b = (unsigned short*)d_ws;           // bf16 W1 (768 KB)
    float* P = (float*)((char*)d_ws + FOUT * FIN * 2);     // partials (128 KB)

    cvt_w1<<<dim3((FOUT * FIN) / (256 * 8)), dim3(256), 0, stream>>>(W1, W1b);
    pn_gemm<<<dim3((BATCH / BM) * 2), dim3(512), 0, stream>>>(
        stm, nstm, W1b, b1, W2, P);
    finish<<<dim3(BATCH / 256), dim3(256), 0, stream>>>(P, b2, out);
}

// Round 5
// 145.512 us; speedup vs baseline: 1.1248x; 1.1248x over previous
//
#include <hip/hip_runtime.h>
#include <hip/hip_bf16.h>

#define BATCH 16384
#define FIN   768
#define FOUT  512

#define BK 64
#define NT (FIN / BK)   // 12 K-iterations
#define BM 128          // batch rows per block -> 256 GEMM rows (stm+nstm)
#define BN 256          // feature cols per block (N-split x2)

typedef __attribute__((ext_vector_type(8))) short short8;
typedef __attribute__((ext_vector_type(4))) float floatx4;

// packed fp32x2 -> bf16x2, round-to-nearest-even (gfx940+ VOP3)
__device__ __forceinline__ unsigned int cvt_pk_bf16(float a, float b) {
    unsigned int r;
    asm("v_cvt_pk_bf16_f32 %0, %1, %2" : "=v"(r) : "v"(a), "v"(b));
    return r;
}

// async 16B global -> LDS DMA; HW scatters lane i to ldsbase + i*16
__device__ __forceinline__ void load_lds_16(const void* g, void* l) {
    __builtin_amdgcn_global_load_lds(
        (const __attribute__((address_space(1))) unsigned int*)g,
        (__attribute__((address_space(3))) unsigned int*)l,
        16, 0, 0);
}

// Raw barrier with COUNTED vmcnt (T4): allow the 2 B-DMAs for tile t+2 to
// stay in flight across the barrier; guarantees (in-order vmem retirement)
// that tile t+1's DMAs -- issued a full iteration earlier -- have landed.
// lgkmcnt(0) publishes this wave's A ds_writes / drains its frag ds_reads.
#define BAR_VM2() do {                                               \
    __builtin_amdgcn_sched_barrier(0);                               \
    asm volatile("s_waitcnt vmcnt(2) lgkmcnt(0)" ::: "memory");      \
    __builtin_amdgcn_s_barrier();                                    \
    __builtin_amdgcn_sched_barrier(0);                               \
} while (0)

// one-shot W1 fp32 -> bf16 (393216 elems, 8 per thread, 192 blocks)
__global__ __launch_bounds__(256) void cvt_w1(
    const float* __restrict__ W1, unsigned short* __restrict__ W1b)
{
    int base = (blockIdx.x * 256 + threadIdx.x) * 8;
    float4 a = *(const float4*)(W1 + base);
    float4 b = *(const float4*)(W1 + base + 4);
    uint4 o;
    o.x = cvt_pk_bf16(a.x, a.y); o.y = cvt_pk_bf16(a.z, a.w);
    o.z = cvt_pk_bf16(b.x, b.y); o.w = cvt_pk_bf16(b.z, b.w);
    *(uint4*)(W1b + base) = o;
}

// 256 blocks x 1024 threads, 1 block/CU (160 KB LDS). Geometry = verified
// round-3 kernel (16 waves x 64x64 tiles, BM=128 -> 256 GEMM rows, BN=256,
// BK=64). New vs R3:
//  (1) B triple-buffered with depth-2 DMA prefetch + raw s_barrier with
//      s_waitcnt vmcnt(2): the barrier no longer drains the just-issued
//      staging (T4 counted-vmcnt) -- only tile t+1's year-old DMAs must
//      have landed, t+2's ride across.
//  (2) XCD-pair swizzle (proven in R4: FETCH 100->52 MB): the two N-split
//      blocks sharing A-rows run on the same XCD -> A fetched once, halving
//      the post-barrier HBM burst the publish waits on.
// Per-wave vmem issue order each iter: [A-loads(t+1) x8][B-DMA(t+2) x2];
// in-order retirement makes vmcnt(2) the exact "B(t+1) landed" condition.
__global__ __launch_bounds__(1024, 4) void pn_gemm(
    const float* __restrict__ stm, const float* __restrict__ nstm,
    const unsigned short* __restrict__ W1b, const float* __restrict__ b1,
    const float* __restrict__ W2, float* __restrict__ P)
{
    __shared__ __align__(16) unsigned short As[2][256 * 64];  // 2 x 32 KB
    __shared__ __align__(16) unsigned short Bs[3][256 * 64];  // 3 x 32 KB

    const int tid  = threadIdx.x;
    const int lane = tid & 63;
    const int wave = tid >> 6;    // 0..15
    const int wr   = wave >> 2;   // row tile: GEMM rows wr*64 .. +63
    const int wc   = wave & 3;    // col tile: cols wc*64 .. +63 (within BN)
    const int quad = lane >> 4;
    const int l16  = lane & 15;

    // XCD-pair swizzle (bijective: 256 blocks, 8 XCDs, chunk 32): the
    // (bm, n_idx=0/1) pair gets consecutive sbids -> same XCD -> shared L2.
    const int sbid  = (blockIdx.x & 7) * 32 + (blockIdx.x >> 3);
    const int bm    = sbid >> 1;
    const int n_idx = sbid & 1;
    const int b0    = bm * BM;        // batch rows owned by this block
    const int n0    = n_idx * BN;     // feature cols owned by this block

    // ---- A staging: thread covers row arow, chunks ac and ac+4 (16 fp32)
    const int arow = tid >> 2;        // 0..255
    const int ac   = tid & 3;         // low chunk; high chunk = ac+4
    const float* aSrc =
        ((arow < BM) ? stm  + (size_t)(b0 + arow) * FIN
                     : nstm + (size_t)(b0 + arow - BM) * FIN);
    const int aOffLo = arow * 64 + ((ac       ^ (arow & 7)) * 8);  // swizzled
    const int aOffHi = arow * 64 + (((ac + 4) ^ (arow & 7)) * 8);

    // ---- B staging: 2 DMA instrs/wave, J = wave*2+i covers rows J*8..+7.
    // DMA writes lane l -> base + l*16 (row l>>3, slot l&7); source chunk is
    // pre-swizzled so LDS holds slot = chunk ^ (row&7).
    const int brow = lane >> 3;                 // row within 8-group
    const int bch  = (lane & 7) ^ brow;         // swizzled SOURCE chunk
    const unsigned short* bSrc =
        W1b + (size_t)(n0 + brow) * FIN + bch * 8;

    floatx4 acc[4][4];
    #pragma unroll
    for (int i = 0; i < 4; ++i)
        #pragma unroll
        for (int j = 0; j < 4; ++j)
            acc[i][j] = (floatx4)0.0f;

    // ---- prologue: B(0), then A(0) regs, then B(1) (issue order matters:
    // publish(0)'s A-reg wait implies B(0) retired; B(1) stays outstanding)
    #pragma unroll
    for (int i = 0; i < 2; ++i) {
        const int J = wave * 2 + i;
        load_lds_16(bSrc + (size_t)(J * 8) * FIN, &Bs[0][J * 512]);
    }
    float4 ap0 = *(const float4*)(aSrc + ac * 8);
    float4 ap1 = *(const float4*)(aSrc + ac * 8 + 4);
    float4 ap2 = *(const float4*)(aSrc + (ac + 4) * 8);
    float4 ap3 = *(const float4*)(aSrc + (ac + 4) * 8 + 4);
    #pragma unroll
    for (int i = 0; i < 2; ++i) {
        const int J = wave * 2 + i;
        load_lds_16(bSrc + (size_t)(J * 8) * FIN + BK, &Bs[1][J * 512]);
    }

    int bc = 0;   // Bs buffer holding tile t
    for (int t = 0; t < NT; ++t) {
        const int cur = t & 1;

        // publish A(t) (regs loaded last iter; As[cur] reads drained at barrier t-1)
        {
            uint4 o1, o2;
            o1.x = cvt_pk_bf16(ap0.x, ap0.y); o1.y = cvt_pk_bf16(ap0.z, ap0.w);
            o1.z = cvt_pk_bf16(ap1.x, ap1.y); o1.w = cvt_pk_bf16(ap1.z, ap1.w);
            o2.x = cvt_pk_bf16(ap2.x, ap2.y); o2.y = cvt_pk_bf16(ap2.z, ap2.w);
            o2.z = cvt_pk_bf16(ap3.x, ap3.y); o2.w = cvt_pk_bf16(ap3.z, ap3.w);
            *(uint4*)(&As[cur][aOffLo]) = o1;
            *(uint4*)(&As[cur][aOffHi]) = o2;
        }
        BAR_VM2();   // B(t) guaranteed landed; B(t+1) DMAs ride across

        // issue staging — A-loads(t+1) FIRST, then B-DMA(t+2) (newest 2)
        if (t + 1 < NT) {
            const int kn = (t + 1) * BK;
            ap0 = *(const float4*)(aSrc + kn + ac * 8);
            ap1 = *(const float4*)(aSrc + kn + ac * 8 + 4);
            ap2 = *(const float4*)(aSrc + kn + (ac + 4) * 8);
            ap3 = *(const float4*)(aSrc + kn + (ac + 4) * 8 + 4);
        }
        if (t + 2 < NT) {
            int bp = bc + 2; if (bp >= 3) bp -= 3;
            const size_t kn2 = (size_t)(t + 2) * BK;
            #pragma unroll
            for (int i = 0; i < 2; ++i) {
                const int J = wave * 2 + i;
                load_lds_16(bSrc + (size_t)(J * 8) * FIN + kn2,
                            &Bs[bp][J * 512]);
            }
        }

        // compute tile t: two K=32 halves; per half, 8 ds_read + 16 MFMA
        #pragma unroll
        for (int kk = 0; kk < 2; ++kk) {
            const int c = kk * 4 + quad;   // chunk index 0..7
            short8 af[4], bfr[4];
            #pragma unroll
            for (int mi = 0; mi < 4; ++mi) {
                const int m = wr * 64 + mi * 16 + l16;
                af[mi] = *(const short8*)(&As[cur][m * 64 + ((c ^ (m & 7)) * 8)]);
            }
            #pragma unroll
            for (int ni = 0; ni < 4; ++ni) {
                const int n = wc * 64 + ni * 16 + l16;
                bfr[ni] = *(const short8*)(&Bs[bc][n * 64 + ((c ^ (n & 7)) * 8)]);
            }
            #pragma unroll
            for (int mi = 0; mi < 4; ++mi)
                #pragma unroll
                for (int ni = 0; ni < 4; ++ni)
                    acc[mi][ni] = __builtin_amdgcn_mfma_f32_16x16x32_bf16(
                        af[mi], bfr[ni], acc[mi][ni], 0, 0, 0);
        }

        bc = (bc == 2) ? 0 : bc + 1;
    }

    // ---- fused epilogue. C/D layout: col = lane&15, row = quad*4 + reg.
    // GEMM rows 0-127 (wr 0,1) = stm -> W2[0..511];
    // rows 128-255 (wr 2,3) = nstm -> W2[512..1023]. wr is wave-uniform.
    float b1v[4], w2v[4];
    const float* w2base = (wr < 2) ? W2 : W2 + FOUT;
    #pragma unroll
    for (int ni = 0; ni < 4; ++ni) {
        int col = n0 + wc * 64 + ni * 16 + l16;
        b1v[ni] = b1[col];
        w2v[ni] = w2base[col];
    }

    __syncthreads();                 // full drain; reuse As
    float* Epi = (float*)As;         // [256 rows][4 wave-cols] partials (4 KB)

    #pragma unroll
    for (int mi = 0; mi < 4; ++mi) {
        #pragma unroll
        for (int r = 0; r < 4; ++r) {
            float s = 0.0f;
            #pragma unroll
            for (int ni = 0; ni < 4; ++ni) {
                float h = acc[mi][ni][r] + b1v[ni];
                h = fminf(fmaxf(h, 0.0f), 1.0f);
                s += h * w2v[ni];
            }
            s += __shfl_xor(s, 1);
            s += __shfl_xor(s, 2);
            s += __shfl_xor(s, 4);
            s += __shfl_xor(s, 8);
            if (l16 == 0) {
                Epi[(wr * 64 + mi * 16 + quad * 4 + r) * 4 + wc] = s;
            }
        }
    }
    __syncthreads();

    // batch row i partial over this block's 256 features =
    // stm-row i partials (rows 0-127) + nstm-row i partials (128-255)
    if (tid < BM) {
        float x = 0.0f;
        #pragma unroll
        for (int j = 0; j < 4; ++j)
            x += Epi[tid * 4 + j] + Epi[(tid + BM) * 4 + j];
        P[n_idx * BATCH + b0 + tid] = x;
    }
}

// sum the two N-half partials + bias, sigmoid
__global__ __launch_bounds__(256) void finish(
    const float* __restrict__ P, const float* __restrict__ b2,
    float* __restrict__ out)
{
    int i = blockIdx.x * 256 + threadIdx.x;
    float x = b2[0] + P[i] + P[BATCH + i];
    out[i] = 1.0f / (1.0f + expf(-x));
}

extern "C" void kernel_launch(void* const* d_in, const int* in_sizes, int n_in,
                              void* d_out, int out_size, void* d_ws, size_t ws_size,
                              hipStream_t stream)
{
    (void)in_sizes; (void)n_in; (void)out_size; (void)ws_size;
    const float* stm  = (const float*)d_in[0];
    const float* nstm = (const float*)d_in[1];
    const float* W1   = (const float*)d_in[2];
    const float* b1   = (const float*)d_in[3];
    const float* W2   = (const float*)d_in[4];
    const float* b2   = (const float*)d_in[5];
    float* out = (float*)d_out;
    unsigned short* W1b = (unsigned short*)d_ws;           // bf16 W1 (768 KB)
    float* P = (float*)((char*)d_ws + FOUT * FIN * 2);     // partials (128 KB)

    cvt_w1<<<dim3((FOUT * FIN) / (256 * 8)), dim3(256), 0, stream>>>(W1, W1b);
    pn_gemm<<<dim3((BATCH / BM) * 2), dim3(1024), 0, stream>>>(
        stm, nstm, W1b, b1, W2, P);
    finish<<<dim3(BATCH / 256), dim3(256), 0, stream>>>(P, b2, out);
}